// Round 8
// baseline (406.603 us; speedup 1.0000x reference)
//
#include <hip/hip_runtime.h>
#include <hip/hip_bf16.h>
#include <math.h>

// B=2, N=256, F=64, H=64, HEADS=4, C=256
#define EPSV 1e-5f
#define INFV 1e5f

// ===== DIAGNOSTIC BUILD =====
// Front half (P0 staging + GEMM1/ep1 + GEMM2/ep2 + GEMM3) repeated 8x, idempotently:
// every repeat recomputes the identical LDS state; output = identical to the 1x kernel.
// Purpose: (a) raise kernel above the fill-kernel floor so rocprof top-5 shows its
// counters again (dominated by the front phase); (b) solve T_front = (dur - dur_R7)/7.
#define FRONT_REPS 8

typedef short bf16x8 __attribute__((ext_vector_type(8)));
typedef float f32x4 __attribute__((ext_vector_type(4)));

__device__ __forceinline__ float rcp_f(float x) { return __builtin_amdgcn_rcpf(x); }
__device__ __forceinline__ float silu_f(float v) { return v * rcp_f(1.0f + __expf(-v)); }

__device__ __forceinline__ unsigned short f2bf(float f) {
  unsigned int u = __float_as_uint(f);
  u = (u + 0x7fffu + ((u >> 16) & 1u)) >> 16;   // RNE
  return (unsigned short)u;
}
__device__ __forceinline__ float bf2f(unsigned short h) {
  return __uint_as_float(((unsigned int)h) << 16);
}
__device__ __forceinline__ unsigned int pkbf(float a, float b) {
  float2 f2; f2.x = a; f2.y = b;
  __hip_bfloat162 t = __float22bfloat162_rn(f2);
  unsigned int u;
  __builtin_memcpy(&u, &t, 4);
  return u;
}

// 256x64 @ 64x64 GEMM over 4 waves: A rows from A_lds (stride 72 u16), B cols from B_lds.
__device__ __forceinline__ void gemm64(const unsigned short* A_lds, const unsigned short* B_lds,
                                       int w, int l15, int quad, f32x4 acc[4][4]) {
#pragma unroll
  for (int tr = 0; tr < 4; ++tr)
#pragma unroll
    for (int tc = 0; tc < 4; ++tc)
      acc[tr][tc] = (f32x4){0.f, 0.f, 0.f, 0.f};
#pragma unroll
  for (int ms = 0; ms < 64; ms += 32) {
    bf16x8 af[4], bfr[4];
#pragma unroll
    for (int tr = 0; tr < 4; ++tr)
      af[tr] = *reinterpret_cast<const bf16x8*>(&A_lds[(64 * w + 16 * tr + l15) * 72 + ms + quad * 8]);
#pragma unroll
    for (int tc = 0; tc < 4; ++tc)
      bfr[tc] = *reinterpret_cast<const bf16x8*>(&B_lds[(16 * tc + l15) * 72 + ms + quad * 8]);
#pragma unroll
    for (int tr = 0; tr < 4; ++tr)
#pragma unroll
      for (int tc = 0; tc < 4; ++tc)
        acc[tr][tc] = __builtin_amdgcn_mfma_f32_16x16x32_bf16(af[tr], bfr[tc], acc[tr][tc], 0, 0, 0);
  }
}

// One block per (b,i): 512 blocks x 256 threads (4 waves), 2 blocks/CU.
__global__ __launch_bounds__(256, 2) void k_all(
    const float* __restrict__ h, const float* __restrict__ x, const float* __restrict__ v,
    const float* __restrict__ ew1, const float* __restrict__ eb1,
    const float* __restrict__ ew2, const float* __restrict__ eb2,
    const float* __restrict__ semw, const float* __restrict__ semb,
    const float* __restrict__ pw1, const float* __restrict__ pb1,
    const float* __restrict__ pw2, const float* __restrict__ pb2,
    const float* __restrict__ nw1, const float* __restrict__ nb1,
    const float* __restrict__ nw2, const float* __restrict__ nb2,
    const float* __restrict__ vw1, const float* __restrict__ vb1,
    const float* __restrict__ vw2, const float* __restrict__ vmix,
    const float* __restrict__ lgam, float* __restrict__ out) {

  __shared__ __align__(16) unsigned short TH[256 * 72];    // 36864 B: h_b -> T -> HE -> tail scratch
  __shared__ __align__(16) char R0[9216];   // W1a^T (GEMM1) -> sd (GEMM3 out, fp32)
  __shared__ __align__(16) char R1[9216];   // W2^T  (GEMM2) -> cat/cn/hag
  __shared__ __align__(16) unsigned short E3T[16 * 72];    // [semw|vmix]^T rows 0..7, rows 8..15 zeroed
  __shared__ __align__(16) float4 unit_l[256];             // .xyz = unit, .w = dn
  __shared__ float w1dk[64];                               // ew1 distance row (pre-s1)
  __shared__ float eb1l[64];                               // eb1 (pre-s1)
  __shared__ __align__(16) float bms[256];                 // Bm partials -> P3 scratch

  const int bid = blockIdx.x;            // == bi (0..511)
  const int b   = bid >> 8;
  const int i   = bid & 255;
  const int bi  = bid;
  const int tid = threadIdx.x;
  const int j   = tid;
  const int bj  = (b << 8) | j;

  const int w    = tid >> 6;             // wave 0..3
  const int lid  = tid & 63;
  const int l15  = lid & 15;
  const int quad = lid >> 4;

  unsigned short* E2Ta = (unsigned short*)R0;
  unsigned short* E2Tb = (unsigned short*)R1;
  float*  sd    = (float*)R0;                 // [256*8] (E2Ta dead after GEMM1)
  float4* cat_l = (float4*)R1;                // [256] (E2Tb dead after GEMM2, pre-B1)
  float*  cn_l  = (float*)(R1 + 4096);        // [256]
  float*  hag_l = (float*)(R1 + 5120);        // [256]
  float4* scS   = (float4*)bms;               // slots 0..7
  float4* scP   = (float4*)bms + 8;           // slots 8..11
  float4* scD   = (float4*)bms + 12;          // slots 12..15
  float*  dvs   = bms + 64;                   // 3 floats @ byte 256

  // ===== P-1: L2 warm of tail weights (once; consumed by asm keep-alive after s8) =====
  float warm = 0.f;
  {
#pragma unroll
    for (int q = 0; q < 4; ++q) warm += pw1[(4 * tid + q) * 16];     // 1024 lines
#pragma unroll
    for (int q = 0; q < 6; ++q) warm += nw1[(6 * tid + q) * 16];     // 1536 lines
    warm += pw2[tid * 16] + nw2[tid * 16] + vw1[tid * 16];           // 256 lines each
    if (tid < 64) warm += eb2[tid] + pb1[tid] + pb2[tid] + nb1[tid] +
                          nb2[tid] + vb1[tid] + vw2[tid];
  }

  float xi0, xi1, xi2, dn, ux, uy, uz;

  // =================== FRONT x FRONT_REPS (idempotent) ===================
#pragma unroll 1
  for (int rep = 0; rep < FRONT_REPS; ++rep) {
    // loop-top barrier: previous rep's sd writes / ep reads done before restage
    __syncthreads();
    asm volatile("" ::: "memory");   // force real reloads; kill cross-rep CSE

    // ================= P0: staging =================
    xi0 = x[bi * 3 + 0]; xi1 = x[bi * 3 + 1]; xi2 = x[bi * 3 + 2];
    const float dx = x[bj * 3 + 0] - xi0;
    const float dy = x[bj * 3 + 1] - xi1;
    const float dz = x[bj * 3 + 2] - xi2;
    dn = sqrtf(dx * dx + dy * dy + dz * dz + EPSV);
    const float invn = rcp_f(dn + EPSV);
    ux = dx * invn; uy = dy * invn; uz = dz * invn;
    unit_l[j] = make_float4(ux, uy, uz, dn);

    {
      const float4* hb4 = reinterpret_cast<const float4*>(h + (size_t)(b << 8) * 64);
#pragma unroll
      for (int q = 0; q < 16; ++q) {
        int idx = q * 256 + tid;            // 0..4095 float4s
        float4 f4 = hb4[idx];
        int row = idx >> 4, c4 = idx & 15;
        uint2 pk;
        pk.x = pkbf(f4.x, f4.y);
        pk.y = pkbf(f4.z, f4.w);
        *reinterpret_cast<uint2*>(&TH[row * 72 + c4 * 4]) = pk;
      }
    }
#pragma unroll
    for (int q = 0; q < 16; ++q) {
      int idx = q * 256 + tid;              // f*64+k
      E2Ta[(idx & 63) * 72 + (idx >> 6)] = f2bf(ew1[idx]);
    }
#pragma unroll
    for (int q = 0; q < 16; ++q) {
      int idx = q * 256 + tid;
      E2Tb[(idx & 63) * 72 + (idx >> 6)] = f2bf(ew2[idx]);
    }
#pragma unroll
    for (int q = 0; q < 2; ++q) {
      int idx = q * 256 + tid;              // n 0..7
      int n = idx >> 6, kk = idx & 63;
      E3T[n * 72 + kk] = f2bf((n < 4) ? semw[kk * 4 + n] : vmix[kk * 4 + (n - 4)]);
      E3T[(8 + n) * 72 + kk] = 0;
    }
    if (tid < 64) { w1dk[tid] = ew1[128 * 64 + tid]; eb1l[tid] = eb1[tid]; }
    // Bm partials (fp32 exact)
    {
      int s = tid >> 6, k = tid & 63;
      const float* hrow = h + (size_t)bi * 64;     // wave-uniform -> scalar loads
      float bp = 0.f;
#pragma unroll
      for (int f2 = 0; f2 < 16; ++f2) {
        int f = s * 16 + f2;
        bp += hrow[f] * ew1[(64 + f) * 64 + k];
      }
      bms[s * 64 + k] = bp;
    }
    __syncthreads();                                               // s1

    // ================= P1: GEMM1 (h_b @ W1a) =================
    f32x4 acc[4][4];
    gemm64(TH, E2Ta, w, l15, quad, acc);
    // NO barrier: ep1 rewrites exactly the rows [64w,64w+64) this wave read.

    // ep1: T = silu(A + addk + dn*w1dk) -> TH
#pragma unroll
    for (int tc = 0; tc < 4; ++tc) {
      int kc = 16 * tc + l15;
      float wd = w1dk[kc];
      float ak = eb1l[kc] + bms[kc] + bms[64 + kc] + bms[128 + kc] + bms[192 + kc];
#pragma unroll
      for (int tr = 0; tr < 4; ++tr)
#pragma unroll
        for (int r = 0; r < 4; ++r) {
          int row = 64 * w + 16 * tr + quad * 4 + r;
          TH[row * 72 + kc] = f2bf(silu_f(acc[tr][tc][r] + ak + unit_l[row].w * wd));
        }
    }
    __syncthreads();                                               // s3 (T rows cross waves)

    // ================= P2: GEMM2 (HE = T @ W2) =================
    gemm64(TH, E2Tb, w, l15, quad, acc);
    // NO barrier: ep2 rewrites the wave's own rows.
#pragma unroll
    for (int tc = 0; tc < 4; ++tc) {
      float b2 = eb2[16 * tc + l15];
#pragma unroll
      for (int tr = 0; tr < 4; ++tr)
#pragma unroll
        for (int r = 0; r < 4; ++r) {
          int row = 64 * w + 16 * tr + quad * 4 + r;
          TH[row * 72 + 16 * tc + l15] = f2bf(silu_f(acc[tr][tc][r] + b2));
        }
    }
    // NO barrier: GEMM3 reads the wave's own rows (same-wave RAW).

    // ================= P2b: GEMM3 (HE @ [semw|vmix]) =================
    f32x4 acc3[4];
#pragma unroll
    for (int tr = 0; tr < 4; ++tr) acc3[tr] = (f32x4){0.f, 0.f, 0.f, 0.f};
#pragma unroll
    for (int ms = 0; ms < 64; ms += 32) {
      bf16x8 b3 = *reinterpret_cast<const bf16x8*>(&E3T[l15 * 72 + ms + quad * 8]);
#pragma unroll
      for (int tr = 0; tr < 4; ++tr) {
        bf16x8 a3 = *reinterpret_cast<const bf16x8*>(&TH[(64 * w + 16 * tr + l15) * 72 + ms + quad * 8]);
        acc3[tr] = __builtin_amdgcn_mfma_f32_16x16x32_bf16(a3, b3, acc3[tr], 0, 0, 0);
      }
    }
    // sd overlays R0 (E2Ta reads done; restaged next rep before any GEMM1 read).
    if (l15 < 8) {
#pragma unroll
      for (int tr = 0; tr < 4; ++tr)
#pragma unroll
        for (int r = 0; r < 4; ++r)
          sd[(64 * w + 16 * tr + quad * 4 + r) * 8 + l15] = acc3[tr][r];
    }
    // NO barrier: P3 thread j reads sd rows written by its own wave.
  }

  // ================= P3: attentions (thread = j), 3 barriers =================
  float4 s01 = *reinterpret_cast<const float4*>(sd + j * 8);       // sem logits (pre-bias)
  float4 s23 = *reinterpret_cast<const float4*>(sd + j * 8 + 4);   // vmix dots
  float4 sbv = *reinterpret_cast<const float4*>(semb);
  const float diag = (j == i) ? INFV : 0.0f;
  float4 sl;
  sl.x = s01.x + sbv.x; sl.y = s01.y + sbv.y; sl.z = s01.z + sbv.z; sl.w = s01.w + sbv.w;
  sl.x = ((sl.x > 0.f) ? sl.x : 0.2f * sl.x) - diag;
  sl.y = ((sl.y > 0.f) ? sl.y : 0.2f * sl.y) - diag;
  sl.z = ((sl.z > 0.f) ? sl.z : 0.2f * sl.z) - diag;
  sl.w = ((sl.w > 0.f) ? sl.w : 0.2f * sl.w) - diag;

  float4 lg4 = *reinterpret_cast<const float4*>(lgam);
  const float dni = dn + diag;
  float4 e_eu = make_float4(__expf(-dni * __expf(lg4.x)), __expf(-dni * __expf(lg4.y)),
                            __expf(-dni * __expf(lg4.z)), __expf(-dni * __expf(lg4.w)));
  // sem logits: LeakyReLU outputs << 88 off-diagonal; diag -1e5 -> exp == 0.
  float4 e_sem = make_float4(__expf(sl.x), __expf(sl.y), __expf(sl.z), __expf(sl.w));

  float4 a8 = e_eu, b8 = e_sem;
#pragma unroll
  for (int off = 32; off >= 1; off >>= 1) {
    a8.x += __shfl_xor(a8.x, off); a8.y += __shfl_xor(a8.y, off);
    a8.z += __shfl_xor(a8.z, off); a8.w += __shfl_xor(a8.w, off);
    b8.x += __shfl_xor(b8.x, off); b8.y += __shfl_xor(b8.y, off);
    b8.z += __shfl_xor(b8.z, off); b8.w += __shfl_xor(b8.w, off);
  }
  if (lid == 0) { scS[w] = a8; scS[4 + w] = b8; }
  __syncthreads();   // B1 (also: all sd/E2T reads precede cat_l writes)
  float4 Se, Ss;
  {
    float4 r0 = scS[0], r1 = scS[1], r2 = scS[2], r3 = scS[3];
    Se = make_float4(r0.x + r1.x + r2.x + r3.x, r0.y + r1.y + r2.y + r3.y,
                     r0.z + r1.z + r2.z + r3.z, r0.w + r1.w + r2.w + r3.w);
    float4 s0 = scS[4], s1 = scS[5], s2 = scS[6], s3 = scS[7];
    Ss = make_float4(s0.x + s1.x + s2.x + s3.x, s0.y + s1.y + s2.y + s3.y,
                     s0.z + s1.z + s2.z + s3.z, s0.w + s1.w + s2.w + s3.w);
  }

  float4 p = make_float4((e_eu.x * rcp_f(Se.x)) * (e_sem.x * rcp_f(Ss.x)),
                         (e_eu.y * rcp_f(Se.y)) * (e_sem.y * rcp_f(Ss.y)),
                         (e_eu.z * rcp_f(Se.z)) * (e_sem.z * rcp_f(Ss.z)),
                         (e_eu.w * rcp_f(Se.w)) * (e_sem.w * rcp_f(Ss.w)));
  float4 ep = make_float4(__expf(p.x), __expf(p.y), __expf(p.z), __expf(p.w));
  float4 sp8 = ep;
#pragma unroll
  for (int off = 32; off >= 1; off >>= 1) {
    sp8.x += __shfl_xor(sp8.x, off); sp8.y += __shfl_xor(sp8.y, off);
    sp8.z += __shfl_xor(sp8.z, off); sp8.w += __shfl_xor(sp8.w, off);
  }
  if (lid == 0) scP[w] = sp8;
  __syncthreads();   // B2
  float4 Sp;
  {
    float4 r0 = scP[0], r1 = scP[1], r2 = scP[2], r3 = scP[3];
    Sp = make_float4(r0.x + r1.x + r2.x + r3.x, r0.y + r1.y + r2.y + r3.y,
                     r0.z + r1.z + r2.z + r3.z, r0.w + r1.w + r2.w + r3.w);
  }
  float4 catt = make_float4(ep.x * rcp_f(Sp.x), ep.y * rcp_f(Sp.y),
                            ep.z * rcp_f(Sp.z), ep.w * rcp_f(Sp.w));
  cat_l[j] = catt;   // sd fully consumed before B1

  float s = catt.x * s23.x + catt.y * s23.y + catt.z * s23.z + catt.w * s23.w;
  float dvx = s * ux, dvy = s * uy, dvz = s * uz;
#pragma unroll
  for (int off = 32; off >= 1; off >>= 1) {
    dvx += __shfl_xor(dvx, off); dvy += __shfl_xor(dvy, off); dvz += __shfl_xor(dvz, off);
  }
  if (lid == 0) scD[w] = make_float4(dvx, dvy, dvz, 0.f);
  __syncthreads();   // B3 (publishes cat_l for P4)
  if (j == 0) {
    float4 r0 = scD[0], r1 = scD[1], r2 = scD[2], r3 = scD[3];
    const float inv = 1.0f / 256.0f;
    dvs[0] = (r0.x + r1.x + r2.x + r3.x) * inv;
    dvs[1] = (r0.y + r1.y + r2.y + r3.y) * inv;
    dvs[2] = (r0.z + r1.z + r2.z + r3.z) * inv;
  }

  // ========== P4: comb_sum / h_agg (DS-lean remap) ==========
  {
    const int jg   = lid >> 2;               // 0..15
    const int ksub = lid & 3;                // 0..3
    const int kb   = 16 * w + 4 * ksub;      // 4 consecutive k's
    float agg[4][4], ax[4][4], ay[4][4], az[4][4];
#pragma unroll
    for (int kk = 0; kk < 4; ++kk)
#pragma unroll
      for (int hd = 0; hd < 4; ++hd) {
        agg[kk][hd] = 0.f; ax[kk][hd] = 0.f; ay[kk][hd] = 0.f; az[kk][hd] = 0.f;
      }
#pragma unroll 4
    for (int jr = 0; jr < 16; ++jr) {
      int jj = jr * 16 + jg;
      ushort4 hv4 = *reinterpret_cast<const ushort4*>(&TH[jj * 72 + kb]);
      float4 ca = cat_l[jj];
      float4 u  = unit_l[jj];
      float hev[4] = { bf2f(hv4.x), bf2f(hv4.y), bf2f(hv4.z), bf2f(hv4.w) };
#pragma unroll
      for (int kk = 0; kk < 4; ++kk) {
        float c0 = hev[kk] * ca.x, c1 = hev[kk] * ca.y, c2 = hev[kk] * ca.z, c3 = hev[kk] * ca.w;
        agg[kk][0] += c0; agg[kk][1] += c1; agg[kk][2] += c2; agg[kk][3] += c3;
        ax[kk][0] += c0 * u.x; ay[kk][0] += c0 * u.y; az[kk][0] += c0 * u.z;
        ax[kk][1] += c1 * u.x; ay[kk][1] += c1 * u.y; az[kk][1] += c1 * u.z;
        ax[kk][2] += c2 * u.x; ay[kk][2] += c2 * u.y; az[kk][2] += c2 * u.z;
        ax[kk][3] += c3 * u.x; ay[kk][3] += c3 * u.y; az[kk][3] += c3 * u.z;
      }
    }
#pragma unroll
    for (int off = 4; off <= 32; off <<= 1)
#pragma unroll
      for (int kk = 0; kk < 4; ++kk)
#pragma unroll
        for (int hd = 0; hd < 4; ++hd) {
          agg[kk][hd] += __shfl_xor(agg[kk][hd], off);
          ax[kk][hd]  += __shfl_xor(ax[kk][hd], off);
          ay[kk][hd]  += __shfl_xor(ay[kk][hd], off);
          az[kk][hd]  += __shfl_xor(az[kk][hd], off);
        }
    if (jg == 0) {
      const float inv = 1.0f / 256.0f;
#pragma unroll
      for (int kk = 0; kk < 4; ++kk) {
        int k = kb + kk;
        f32x4 cnv, hgv;
#pragma unroll
        for (int hd = 0; hd < 4; ++hd) {
          float cx = ax[kk][hd] * inv, cy = ay[kk][hd] * inv, cz = az[kk][hd] * inv;
          cnv[hd] = cx * cx + cy * cy + cz * cz;
          hgv[hd] = agg[kk][hd];
        }
        *reinterpret_cast<f32x4*>(&cn_l[k * 4])  = cnv;
        *reinterpret_cast<f32x4*>(&hag_l[k * 4]) = hgv;
      }
    }
  }
  __syncthreads();                                               // s8: cn/hag cross-wave; TH freed

  // warm value consumed here: forces the prefetch loads to retire (long done by now)
  asm volatile("" :: "v"(warm));

  // ============== P5a: tail stage A, 4-wave parallel ==============
  {
    const int k = lid;
    float* tmpg = (float*)TH;                  // TH free after s8
    float a1 = 0.f;
#pragma unroll 16
    for (int m2 = 0; m2 < 64; ++m2) {
      int m = 64 * w + m2;
      a1 += cn_l[m] * pw1[m * 64 + k];
    }
    tmpg[w * 64 + k] = a1;
    if (w == 1 || w == 2) {
      float a2 = 0.f;
      int base = (w - 1) * 128;
#pragma unroll 16
      for (int m2 = 0; m2 < 128; ++m2) {
        int m = base + m2;
        a2 += hag_l[m] * nw1[(64 + m) * 64 + k];
      }
      tmpg[256 + (w - 1) * 64 + k] = a2;
    } else if (w == 3) {
      float a2 = 0.f;
      const float* hrow = h + (size_t)bi * 64;
#pragma unroll 16
      for (int m = 0; m < 64; ++m) a2 += hrow[m] * nw1[m * 64 + k];
      tmpg[384 + k] = a2;
    }
  }
  __syncthreads();                                               // s9

  // ============== P5b: dependent chain, wave 0 only, zero barriers ==============
  if (w == 0) {
    const int k = lid;
    float* tmpg = (float*)TH;
    float* sh2  = tmpg + 512;                 // wave-local scratch (lgkmcnt-ordered)

    float m1 = silu_f(pb1[k] + tmpg[k] + tmpg[64 + k] + tmpg[128 + k] + tmpg[192 + k]);
    sh2[k] = m1;

    // post2: 64 -> 64
    float a = 0.f;
#pragma unroll 16
    for (int m = 0; m < 64; ++m) a += sh2[m] * pw2[m * 64 + k];
    float hcomb = silu_f(pb2[k] + a);
    sh2[64 + k] = hcomb;

    // node1: add hcomb part to precomputed h/hag partials
    a = nb1[k] + tmpg[256 + k] + tmpg[320 + k] + tmpg[384 + k];
#pragma unroll 16
    for (int m = 0; m < 64; ++m) a += sh2[64 + m] * nw1[(320 + m) * 64 + k];
    sh2[128 + k] = silu_f(a);

    // node2: 64 -> 64, residual
    a = 0.f;
#pragma unroll 16
    for (int m = 0; m < 64; ++m) a += sh2[128 + m] * nw2[m * 64 + k];
    float hn = h[(size_t)bi * 64 + k] + silu_f(nb2[k] + a);
    out[(size_t)bi * 64 + k] = hn;
    sh2[192 + k] = hn;

    // vel: 64 -> 64 -> scalar
    a = 0.f;
#pragma unroll 16
    for (int m = 0; m < 64; ++m) a += sh2[192 + m] * vw1[m * 64 + k];
    float vh = silu_f(vb1[k] + a) * vw2[k];
#pragma unroll
    for (int off = 32; off >= 1; off >>= 1) vh += __shfl_xor(vh, off);

    if (k == 0) {
      const float xi[3] = {xi0, xi1, xi2};
#pragma unroll
      for (int d = 0; d < 3; ++d) {
        float vn = dvs[d] + vh * v[bi * 3 + d];
        out[32768 + bi * 3 + d] = xi[d] + vn;
        out[34304 + bi * 3 + d] = vn;
      }
    }
  }
}

extern "C" void kernel_launch(void* const* d_in, const int* in_sizes, int n_in,
                              void* d_out, int out_size, void* d_ws, size_t ws_size,
                              hipStream_t stream) {
  const float* h    = (const float*)d_in[0];
  const float* x    = (const float*)d_in[1];
  const float* v    = (const float*)d_in[2];
  const float* ew1  = (const float*)d_in[3];
  const float* eb1  = (const float*)d_in[4];
  const float* ew2  = (const float*)d_in[5];
  const float* eb2  = (const float*)d_in[6];
  const float* semw = (const float*)d_in[7];
  const float* semb = (const float*)d_in[8];
  const float* pw1  = (const float*)d_in[9];
  const float* pb1  = (const float*)d_in[10];
  const float* pw2  = (const float*)d_in[11];
  const float* pb2  = (const float*)d_in[12];
  const float* nw1  = (const float*)d_in[13];
  const float* nb1  = (const float*)d_in[14];
  const float* nw2  = (const float*)d_in[15];
  const float* nb2  = (const float*)d_in[16];
  const float* vw1  = (const float*)d_in[17];
  const float* vb1  = (const float*)d_in[18];
  const float* vw2  = (const float*)d_in[19];
  const float* vmix = (const float*)d_in[20];
  const float* lgam = (const float*)d_in[21];
  float* out = (float*)d_out;

  k_all<<<512, 256, 0, stream>>>(h, x, v, ew1, eb1, ew2, eb2, semw, semb,
                                 pw1, pb1, pw2, pb2, nw1, nb1, nw2, nb2,
                                 vw1, vb1, vw2, vmix, lgam, out);
}

// Round 9
// 130.034 us; speedup vs baseline: 3.1269x; 3.1269x over previous
//
#include <hip/hip_runtime.h>
#include <hip/hip_bf16.h>
#include <math.h>

// B=2, N=256, F=64, H=64, HEADS=4, C=256
#define EPSV 1e-5f
#define INFV 1e5f

typedef short bf16x8 __attribute__((ext_vector_type(8)));
typedef float f32x4 __attribute__((ext_vector_type(4)));

__device__ __forceinline__ float rcp_f(float x) { return __builtin_amdgcn_rcpf(x); }
__device__ __forceinline__ float silu_f(float v) { return v * rcp_f(1.0f + __expf(-v)); }

__device__ __forceinline__ unsigned short f2bf(float f) {
  unsigned int u = __float_as_uint(f);
  u = (u + 0x7fffu + ((u >> 16) & 1u)) >> 16;   // RNE
  return (unsigned short)u;
}
__device__ __forceinline__ float bf2f(unsigned short h) {
  return __uint_as_float(((unsigned int)h) << 16);
}

// ws layout (u16 units): [0,4096) W1a^T fragments; [4096,8192) W2^T fragments;
// [8192,9216) E3 fragments (rows>=8 zero); [9216,41984) h as bf16 [2][256][64].
// Fragment order: fi = tc*2+ms (E3: fi=ms); u16 idx = fi*512 + lane*8 + e;
// value = W^T[k= tc*16+(lane&15)][f = ms*32+(lane>>4)*8+e].
__global__ __launch_bounds__(256) void k_prep(
    const float* __restrict__ ew1, const float* __restrict__ ew2,
    const float* __restrict__ semw, const float* __restrict__ vmix,
    const float* __restrict__ h, unsigned short* __restrict__ ws16) {
  int gid = blockIdx.x * 256 + threadIdx.x;        // 0..41983
  if (gid < 4096) {
    int fi = gid >> 9, l = (gid >> 3) & 63, e = gid & 7;
    int tc = fi >> 1, ms = fi & 1;
    int f = ms * 32 + (l >> 4) * 8 + e, k = tc * 16 + (l & 15);
    ws16[gid] = f2bf(ew1[f * 64 + k]);
  } else if (gid < 8192) {
    int t = gid - 4096;
    int fi = t >> 9, l = (t >> 3) & 63, e = t & 7;
    int tc = fi >> 1, ms = fi & 1;
    int f = ms * 32 + (l >> 4) * 8 + e, k = tc * 16 + (l & 15);
    ws16[gid] = f2bf(ew2[f * 64 + k]);
  } else if (gid < 9216) {
    int t = gid - 8192;
    int fi = t >> 9, l = (t >> 3) & 63, e = t & 7;
    int n = l & 15, kk = fi * 32 + (l >> 4) * 8 + e;
    float v = (n < 4) ? semw[kk * 4 + n] : (n < 8 ? vmix[kk * 4 + (n - 4)] : 0.f);
    ws16[gid] = f2bf(v);
  } else {
    ws16[gid] = f2bf(h[gid - 9216]);
  }
}

// One block per (b,i): 512 blocks x 256 threads (4 waves), LDS 49664 B -> 3 blocks/CU.
// Front redesigned per R8 diagnostic (front = 90% of kernel, mostly stall):
// all GEMM B-operands load DIRECTLY from ws fragments into registers (no LDS staging,
// no f2bf, no transpose scatter); TH staged from pre-converted bf16 h.
__global__ __launch_bounds__(256, 3) void k_all(
    const float* __restrict__ h, const float* __restrict__ x, const float* __restrict__ v,
    const float* __restrict__ ew1, const float* __restrict__ eb1,
    const float* __restrict__ eb2,
    const float* __restrict__ semb,
    const float* __restrict__ pw1, const float* __restrict__ pb1,
    const float* __restrict__ pw2, const float* __restrict__ pb2,
    const float* __restrict__ nw1, const float* __restrict__ nb1,
    const float* __restrict__ nw2, const float* __restrict__ nb2,
    const float* __restrict__ vw1, const float* __restrict__ vb1,
    const float* __restrict__ vw2,
    const float* __restrict__ lgam,
    const unsigned short* __restrict__ wsb, float* __restrict__ out) {

  __shared__ __align__(16) unsigned short TH[256 * 72];    // 36864 B: h_b -> T -> HE -> tail scratch
  __shared__ __align__(16) float sd[2048];                 // 8192 B: GEMM3 out -> cat/cn/hag
  __shared__ __align__(16) float4 unit_l[256];             // .xyz = unit, .w = dn
  __shared__ float w1dk[64];                               // ew1 distance row (pre-s1)
  __shared__ float eb1l[64];                               // eb1 (pre-s1)
  __shared__ __align__(16) float bms[256];                 // Bm partials -> P3 scratch

  const int bid = blockIdx.x;            // == bi (0..511)
  const int b   = bid >> 8;
  const int i   = bid & 255;
  const int bi  = bid;
  const int tid = threadIdx.x;
  const int j   = tid;
  const int bj  = (b << 8) | j;

  const int w    = tid >> 6;             // wave 0..3
  const int lid  = tid & 63;
  const int l15  = lid & 15;
  const int quad = lid >> 4;

  float4* cat_l = (float4*)sd;                // [256] (sd consumed pre-B1; cat written post-B2)
  float*  cn_l  = sd + 1024;                  // [256]
  float*  hag_l = sd + 1280;                  // [256]
  float4* scS   = (float4*)bms;               // slots 0..7
  float4* scP   = (float4*)bms + 8;           // slots 8..11
  float4* scD   = (float4*)bms + 12;          // slots 12..15
  float*  dvs   = bms + 64;                   // 3 floats @ byte 256

  // ===== P-1: L2 warm of tail weights (consumed by asm keep-alive after s8) =====
  float warm = 0.f;
  {
#pragma unroll
    for (int q = 0; q < 4; ++q) warm += pw1[(4 * tid + q) * 16];     // 1024 lines
#pragma unroll
    for (int q = 0; q < 6; ++q) warm += nw1[(6 * tid + q) * 16];     // 1536 lines
    warm += pw2[tid * 16] + nw2[tid * 16] + vw1[tid * 16];           // 256 lines each
    if (tid < 64) warm += eb2[tid] + pb1[tid] + pb2[tid] + nb1[tid] +
                          nb2[tid] + vb1[tid] + vw2[tid];
  }

  // ===== B fragments for GEMM1: registers, one coalesced 16 B load per fragment =====
  bf16x8 B1f[8];
#pragma unroll
  for (int fi = 0; fi < 8; ++fi)
    B1f[fi] = *reinterpret_cast<const bf16x8*>(wsb + fi * 512 + lid * 8);

  // ================= P0: staging =================
  const float xi0 = x[bi * 3 + 0], xi1 = x[bi * 3 + 1], xi2 = x[bi * 3 + 2];
  const float dx = x[bj * 3 + 0] - xi0;
  const float dy = x[bj * 3 + 1] - xi1;
  const float dz = x[bj * 3 + 2] - xi2;
  const float dn = sqrtf(dx * dx + dy * dy + dz * dz + EPSV);
  const float invn = rcp_f(dn + EPSV);
  const float ux = dx * invn, uy = dy * invn, uz = dz * invn;
  unit_l[j] = make_float4(ux, uy, uz, dn);

  // TH <- bf16 h_b from ws (no conversion, coalesced 16 B both sides)
#pragma unroll
  for (int q = 0; q < 8; ++q) {
    int c = q * 256 + tid;               // 0..2047 chunks of 8 bf16
    bf16x8 hv = *reinterpret_cast<const bf16x8*>(wsb + 9216 + (b << 14) + c * 8);
    *reinterpret_cast<bf16x8*>(&TH[(c >> 3) * 72 + (c & 7) * 8]) = hv;
  }
  if (tid < 64) { w1dk[tid] = ew1[128 * 64 + tid]; eb1l[tid] = eb1[tid]; }
  // Bm partials (fp32 exact)
  {
    int s = tid >> 6, k = tid & 63;
    const float* hrow = h + (size_t)bi * 64;     // wave-uniform -> scalar loads
    float bp = 0.f;
#pragma unroll
    for (int f2 = 0; f2 < 16; ++f2) {
      int f = s * 16 + f2;
      bp += hrow[f] * ew1[(64 + f) * 64 + k];
    }
    bms[s * 64 + k] = bp;
  }
  __syncthreads();                                               // s1

  // ================= P1: GEMM1 (h_b @ W1a), B from registers =================
  f32x4 acc[4][4];
#pragma unroll
  for (int tr = 0; tr < 4; ++tr)
#pragma unroll
    for (int tc = 0; tc < 4; ++tc)
      acc[tr][tc] = (f32x4){0.f, 0.f, 0.f, 0.f};
#pragma unroll
  for (int ms = 0; ms < 2; ++ms) {
    bf16x8 af[4];
#pragma unroll
    for (int tr = 0; tr < 4; ++tr)
      af[tr] = *reinterpret_cast<const bf16x8*>(&TH[(64 * w + 16 * tr + l15) * 72 + ms * 32 + quad * 8]);
#pragma unroll
    for (int tr = 0; tr < 4; ++tr)
#pragma unroll
      for (int tc = 0; tc < 4; ++tc)
        acc[tr][tc] = __builtin_amdgcn_mfma_f32_16x16x32_bf16(af[tr], B1f[tc * 2 + ms], acc[tr][tc], 0, 0, 0);
  }
  // NO barrier: ep1 rewrites exactly the rows [64w,64w+64) this wave read.

  // ep1: T = silu(A + addk + dn*w1dk) -> TH
#pragma unroll
  for (int tc = 0; tc < 4; ++tc) {
    int kc = 16 * tc + l15;
    float wd = w1dk[kc];
    float ak = eb1l[kc] + bms[kc] + bms[64 + kc] + bms[128 + kc] + bms[192 + kc];
#pragma unroll
    for (int tr = 0; tr < 4; ++tr)
#pragma unroll
      for (int r = 0; r < 4; ++r) {
        int row = 64 * w + 16 * tr + quad * 4 + r;
        TH[row * 72 + kc] = f2bf(silu_f(acc[tr][tc][r] + ak + unit_l[row].w * wd));
      }
  }
  // B fragments for GEMM2 (latency hides under s3 barrier convergence)
  bf16x8 B2f[8];
#pragma unroll
  for (int fi = 0; fi < 8; ++fi)
    B2f[fi] = *reinterpret_cast<const bf16x8*>(wsb + 4096 + fi * 512 + lid * 8);
  __syncthreads();                                               // s3 (T rows cross waves)

  // ================= P2: GEMM2 (HE = T @ W2), B from registers =================
#pragma unroll
  for (int tr = 0; tr < 4; ++tr)
#pragma unroll
    for (int tc = 0; tc < 4; ++tc)
      acc[tr][tc] = (f32x4){0.f, 0.f, 0.f, 0.f};
#pragma unroll
  for (int ms = 0; ms < 2; ++ms) {
    bf16x8 af[4];
#pragma unroll
    for (int tr = 0; tr < 4; ++tr)
      af[tr] = *reinterpret_cast<const bf16x8*>(&TH[(64 * w + 16 * tr + l15) * 72 + ms * 32 + quad * 8]);
#pragma unroll
    for (int tr = 0; tr < 4; ++tr)
#pragma unroll
      for (int tc = 0; tc < 4; ++tc)
        acc[tr][tc] = __builtin_amdgcn_mfma_f32_16x16x32_bf16(af[tr], B2f[tc * 2 + ms], acc[tr][tc], 0, 0, 0);
  }
  // E3 fragments for GEMM3
  bf16x8 E3f[2];
#pragma unroll
  for (int fi = 0; fi < 2; ++fi)
    E3f[fi] = *reinterpret_cast<const bf16x8*>(wsb + 8192 + fi * 512 + lid * 8);
  // NO barrier: ep2 rewrites the wave's own rows.
#pragma unroll
  for (int tc = 0; tc < 4; ++tc) {
    float b2 = eb2[16 * tc + l15];
#pragma unroll
    for (int tr = 0; tr < 4; ++tr)
#pragma unroll
      for (int r = 0; r < 4; ++r) {
        int row = 64 * w + 16 * tr + quad * 4 + r;
        TH[row * 72 + 16 * tc + l15] = f2bf(silu_f(acc[tr][tc][r] + b2));
      }
  }
  // NO barrier: GEMM3 reads the wave's own rows (same-wave RAW).

  // ================= P2b: GEMM3 (HE @ [semw|vmix]), B from registers =================
  f32x4 acc3[4];
#pragma unroll
  for (int tr = 0; tr < 4; ++tr) acc3[tr] = (f32x4){0.f, 0.f, 0.f, 0.f};
#pragma unroll
  for (int ms = 0; ms < 2; ++ms) {
#pragma unroll
    for (int tr = 0; tr < 4; ++tr) {
      bf16x8 a3 = *reinterpret_cast<const bf16x8*>(&TH[(64 * w + 16 * tr + l15) * 72 + ms * 32 + quad * 8]);
      acc3[tr] = __builtin_amdgcn_mfma_f32_16x16x32_bf16(a3, E3f[ms], acc3[tr], 0, 0, 0);
    }
  }
  if (l15 < 8) {
#pragma unroll
    for (int tr = 0; tr < 4; ++tr)
#pragma unroll
      for (int r = 0; r < 4; ++r)
        sd[(64 * w + 16 * tr + quad * 4 + r) * 8 + l15] = acc3[tr][r];
  }
  // NO barrier: thread j reads sd rows written by its own wave.

  // ================= P3: attentions (thread = j), 3 barriers =================
  float4 s01 = *reinterpret_cast<const float4*>(sd + j * 8);       // sem logits (pre-bias)
  float4 s23 = *reinterpret_cast<const float4*>(sd + j * 8 + 4);   // vmix dots
  float4 sbv = *reinterpret_cast<const float4*>(semb);
  const float diag = (j == i) ? INFV : 0.0f;
  float4 sl;
  sl.x = s01.x + sbv.x; sl.y = s01.y + sbv.y; sl.z = s01.z + sbv.z; sl.w = s01.w + sbv.w;
  sl.x = ((sl.x > 0.f) ? sl.x : 0.2f * sl.x) - diag;
  sl.y = ((sl.y > 0.f) ? sl.y : 0.2f * sl.y) - diag;
  sl.z = ((sl.z > 0.f) ? sl.z : 0.2f * sl.z) - diag;
  sl.w = ((sl.w > 0.f) ? sl.w : 0.2f * sl.w) - diag;

  float4 lg4 = *reinterpret_cast<const float4*>(lgam);
  const float dni = dn + diag;
  float4 e_eu = make_float4(__expf(-dni * __expf(lg4.x)), __expf(-dni * __expf(lg4.y)),
                            __expf(-dni * __expf(lg4.z)), __expf(-dni * __expf(lg4.w)));
  // sem logits: LeakyReLU outputs << 88 off-diagonal; diag -1e5 -> exp == 0.
  float4 e_sem = make_float4(__expf(sl.x), __expf(sl.y), __expf(sl.z), __expf(sl.w));

  float4 a8 = e_eu, b8 = e_sem;
#pragma unroll
  for (int off = 32; off >= 1; off >>= 1) {
    a8.x += __shfl_xor(a8.x, off); a8.y += __shfl_xor(a8.y, off);
    a8.z += __shfl_xor(a8.z, off); a8.w += __shfl_xor(a8.w, off);
    b8.x += __shfl_xor(b8.x, off); b8.y += __shfl_xor(b8.y, off);
    b8.z += __shfl_xor(b8.z, off); b8.w += __shfl_xor(b8.w, off);
  }
  if (lid == 0) { scS[w] = a8; scS[4 + w] = b8; }
  __syncthreads();   // B1 (all sd reads precede cat_l writes)
  float4 Se, Ss;
  {
    float4 r0 = scS[0], r1 = scS[1], r2 = scS[2], r3 = scS[3];
    Se = make_float4(r0.x + r1.x + r2.x + r3.x, r0.y + r1.y + r2.y + r3.y,
                     r0.z + r1.z + r2.z + r3.z, r0.w + r1.w + r2.w + r3.w);
    float4 s0 = scS[4], s1 = scS[5], s2 = scS[6], s3 = scS[7];
    Ss = make_float4(s0.x + s1.x + s2.x + s3.x, s0.y + s1.y + s2.y + s3.y,
                     s0.z + s1.z + s2.z + s3.z, s0.w + s1.w + s2.w + s3.w);
  }

  float4 p = make_float4((e_eu.x * rcp_f(Se.x)) * (e_sem.x * rcp_f(Ss.x)),
                         (e_eu.y * rcp_f(Se.y)) * (e_sem.y * rcp_f(Ss.y)),
                         (e_eu.z * rcp_f(Se.z)) * (e_sem.z * rcp_f(Ss.z)),
                         (e_eu.w * rcp_f(Se.w)) * (e_sem.w * rcp_f(Ss.w)));
  float4 ep = make_float4(__expf(p.x), __expf(p.y), __expf(p.z), __expf(p.w));
  float4 sp8 = ep;
#pragma unroll
  for (int off = 32; off >= 1; off >>= 1) {
    sp8.x += __shfl_xor(sp8.x, off); sp8.y += __shfl_xor(sp8.y, off);
    sp8.z += __shfl_xor(sp8.z, off); sp8.w += __shfl_xor(sp8.w, off);
  }
  if (lid == 0) scP[w] = sp8;
  __syncthreads();   // B2
  float4 Sp;
  {
    float4 r0 = scP[0], r1 = scP[1], r2 = scP[2], r3 = scP[3];
    Sp = make_float4(r0.x + r1.x + r2.x + r3.x, r0.y + r1.y + r2.y + r3.y,
                     r0.z + r1.z + r2.z + r3.z, r0.w + r1.w + r2.w + r3.w);
  }
  float4 catt = make_float4(ep.x * rcp_f(Sp.x), ep.y * rcp_f(Sp.y),
                            ep.z * rcp_f(Sp.z), ep.w * rcp_f(Sp.w));
  cat_l[j] = catt;   // sd fully consumed before B1

  float s = catt.x * s23.x + catt.y * s23.y + catt.z * s23.z + catt.w * s23.w;
  float dvx = s * ux, dvy = s * uy, dvz = s * uz;
#pragma unroll
  for (int off = 32; off >= 1; off >>= 1) {
    dvx += __shfl_xor(dvx, off); dvy += __shfl_xor(dvy, off); dvz += __shfl_xor(dvz, off);
  }
  if (lid == 0) scD[w] = make_float4(dvx, dvy, dvz, 0.f);
  __syncthreads();   // B3 (publishes cat_l for P4)
  if (j == 0) {
    float4 r0 = scD[0], r1 = scD[1], r2 = scD[2], r3 = scD[3];
    const float inv = 1.0f / 256.0f;
    dvs[0] = (r0.x + r1.x + r2.x + r3.x) * inv;
    dvs[1] = (r0.y + r1.y + r2.y + r3.y) * inv;
    dvs[2] = (r0.z + r1.z + r2.z + r3.z) * inv;
  }

  // ========== P4: comb_sum / h_agg (DS-lean remap) ==========
  {
    const int jg   = lid >> 2;               // 0..15
    const int ksub = lid & 3;                // 0..3
    const int kb   = 16 * w + 4 * ksub;      // 4 consecutive k's
    float agg[4][4], ax[4][4], ay[4][4], az[4][4];
#pragma unroll
    for (int kk = 0; kk < 4; ++kk)
#pragma unroll
      for (int hd = 0; hd < 4; ++hd) {
        agg[kk][hd] = 0.f; ax[kk][hd] = 0.f; ay[kk][hd] = 0.f; az[kk][hd] = 0.f;
      }
#pragma unroll 4
    for (int jr = 0; jr < 16; ++jr) {
      int jj = jr * 16 + jg;
      ushort4 hv4 = *reinterpret_cast<const ushort4*>(&TH[jj * 72 + kb]);
      float4 ca = cat_l[jj];
      float4 u  = unit_l[jj];
      float hev[4] = { bf2f(hv4.x), bf2f(hv4.y), bf2f(hv4.z), bf2f(hv4.w) };
#pragma unroll
      for (int kk = 0; kk < 4; ++kk) {
        float c0 = hev[kk] * ca.x, c1 = hev[kk] * ca.y, c2 = hev[kk] * ca.z, c3 = hev[kk] * ca.w;
        agg[kk][0] += c0; agg[kk][1] += c1; agg[kk][2] += c2; agg[kk][3] += c3;
        ax[kk][0] += c0 * u.x; ay[kk][0] += c0 * u.y; az[kk][0] += c0 * u.z;
        ax[kk][1] += c1 * u.x; ay[kk][1] += c1 * u.y; az[kk][1] += c1 * u.z;
        ax[kk][2] += c2 * u.x; ay[kk][2] += c2 * u.y; az[kk][2] += c2 * u.z;
        ax[kk][3] += c3 * u.x; ay[kk][3] += c3 * u.y; az[kk][3] += c3 * u.z;
      }
    }
#pragma unroll
    for (int off = 4; off <= 32; off <<= 1)
#pragma unroll
      for (int kk = 0; kk < 4; ++kk)
#pragma unroll
        for (int hd = 0; hd < 4; ++hd) {
          agg[kk][hd] += __shfl_xor(agg[kk][hd], off);
          ax[kk][hd]  += __shfl_xor(ax[kk][hd], off);
          ay[kk][hd]  += __shfl_xor(ay[kk][hd], off);
          az[kk][hd]  += __shfl_xor(az[kk][hd], off);
        }
    if (jg == 0) {
      const float inv = 1.0f / 256.0f;
#pragma unroll
      for (int kk = 0; kk < 4; ++kk) {
        int k = kb + kk;
        f32x4 cnv, hgv;
#pragma unroll
        for (int hd = 0; hd < 4; ++hd) {
          float cx = ax[kk][hd] * inv, cy = ay[kk][hd] * inv, cz = az[kk][hd] * inv;
          cnv[hd] = cx * cx + cy * cy + cz * cz;
          hgv[hd] = agg[kk][hd];
        }
        *reinterpret_cast<f32x4*>(&cn_l[k * 4])  = cnv;
        *reinterpret_cast<f32x4*>(&hag_l[k * 4]) = hgv;
      }
    }
  }
  __syncthreads();                                               // s8: cn/hag cross-wave; TH freed

  // warm value consumed here: forces the prefetch loads to retire (long done by now)
  asm volatile("" :: "v"(warm));

  // ============== P5a: tail stage A, 4-wave parallel ==============
  {
    const int k = lid;
    float* tmpg = (float*)TH;                  // TH free after s8
    float a1 = 0.f;
#pragma unroll 16
    for (int m2 = 0; m2 < 64; ++m2) {
      int m = 64 * w + m2;
      a1 += cn_l[m] * pw1[m * 64 + k];
    }
    tmpg[w * 64 + k] = a1;
    if (w == 1 || w == 2) {
      float a2 = 0.f;
      int base = (w - 1) * 128;
#pragma unroll 16
      for (int m2 = 0; m2 < 128; ++m2) {
        int m = base + m2;
        a2 += hag_l[m] * nw1[(64 + m) * 64 + k];
      }
      tmpg[256 + (w - 1) * 64 + k] = a2;
    } else if (w == 3) {
      float a2 = 0.f;
      const float* hrow = h + (size_t)bi * 64;
#pragma unroll 16
      for (int m = 0; m < 64; ++m) a2 += hrow[m] * nw1[m * 64 + k];
      tmpg[384 + k] = a2;
    }
  }
  __syncthreads();                                               // s9

  // ============== P5b: dependent chain, wave 0 only, zero barriers ==============
  if (w == 0) {
    const int k = lid;
    float* tmpg = (float*)TH;
    float* sh2  = tmpg + 512;                 // wave-local scratch (lgkmcnt-ordered)

    float m1 = silu_f(pb1[k] + tmpg[k] + tmpg[64 + k] + tmpg[128 + k] + tmpg[192 + k]);
    sh2[k] = m1;

    // post2: 64 -> 64
    float a = 0.f;
#pragma unroll 16
    for (int m = 0; m < 64; ++m) a += sh2[m] * pw2[m * 64 + k];
    float hcomb = silu_f(pb2[k] + a);
    sh2[64 + k] = hcomb;

    // node1: add hcomb part to precomputed h/hag partials
    a = nb1[k] + tmpg[256 + k] + tmpg[320 + k] + tmpg[384 + k];
#pragma unroll 16
    for (int m = 0; m < 64; ++m) a += sh2[64 + m] * nw1[(320 + m) * 64 + k];
    sh2[128 + k] = silu_f(a);

    // node2: 64 -> 64, residual
    a = 0.f;
#pragma unroll 16
    for (int m = 0; m < 64; ++m) a += sh2[128 + m] * nw2[m * 64 + k];
    float hn = h[(size_t)bi * 64 + k] + silu_f(nb2[k] + a);
    out[(size_t)bi * 64 + k] = hn;
    sh2[192 + k] = hn;

    // vel: 64 -> 64 -> scalar
    a = 0.f;
#pragma unroll 16
    for (int m = 0; m < 64; ++m) a += sh2[192 + m] * vw1[m * 64 + k];
    float vh = silu_f(vb1[k] + a) * vw2[k];
#pragma unroll
    for (int off = 32; off >= 1; off >>= 1) vh += __shfl_xor(vh, off);

    if (k == 0) {
      const float xi[3] = {xi0, xi1, xi2};
#pragma unroll
      for (int d = 0; d < 3; ++d) {
        float vn = dvs[d] + vh * v[bi * 3 + d];
        out[32768 + bi * 3 + d] = xi[d] + vn;
        out[34304 + bi * 3 + d] = vn;
      }
    }
  }
}

extern "C" void kernel_launch(void* const* d_in, const int* in_sizes, int n_in,
                              void* d_out, int out_size, void* d_ws, size_t ws_size,
                              hipStream_t stream) {
  const float* h    = (const float*)d_in[0];
  const float* x    = (const float*)d_in[1];
  const float* v    = (const float*)d_in[2];
  const float* ew1  = (const float*)d_in[3];
  const float* eb1  = (const float*)d_in[4];
  const float* ew2  = (const float*)d_in[5];
  const float* eb2  = (const float*)d_in[6];
  const float* semw = (const float*)d_in[7];
  const float* semb = (const float*)d_in[8];
  const float* pw1  = (const float*)d_in[9];
  const float* pb1  = (const float*)d_in[10];
  const float* pw2  = (const float*)d_in[11];
  const float* pb2  = (const float*)d_in[12];
  const float* nw1  = (const float*)d_in[13];
  const float* nb1  = (const float*)d_in[14];
  const float* nw2  = (const float*)d_in[15];
  const float* nb2  = (const float*)d_in[16];
  const float* vw1  = (const float*)d_in[17];
  const float* vb1  = (const float*)d_in[18];
  const float* vw2  = (const float*)d_in[19];
  const float* vmix = (const float*)d_in[20];
  const float* lgam = (const float*)d_in[21];
  float* out = (float*)d_out;
  unsigned short* ws16 = (unsigned short*)d_ws;

  k_prep<<<164, 256, 0, stream>>>(ew1, ew2, semw, vmix, h, ws16);
  k_all<<<512, 256, 0, stream>>>(h, x, v, ew1, eb1, eb2, semb,
                                 pw1, pb1, pw2, pb2, nw1, nb1, nw2, nb2,
                                 vw1, vb1, vw2, lgam, ws16, out);
}

// Round 10
// 124.075 us; speedup vs baseline: 3.2771x; 1.0480x over previous
//
#include <hip/hip_runtime.h>
#include <hip/hip_bf16.h>
#include <math.h>

// B=2, N=256, F=64, H=64, HEADS=4, C=256
#define EPSV 1e-5f
#define INFV 1e5f

typedef short bf16x8 __attribute__((ext_vector_type(8)));
typedef float f32x4 __attribute__((ext_vector_type(4)));

__device__ __forceinline__ float rcp_f(float x) { return __builtin_amdgcn_rcpf(x); }
__device__ __forceinline__ float silu_f(float v) { return v * rcp_f(1.0f + __expf(-v)); }

__device__ __forceinline__ unsigned short f2bf(float f) {
  unsigned int u = __float_as_uint(f);
  u = (u + 0x7fffu + ((u >> 16) & 1u)) >> 16;   // RNE
  return (unsigned short)u;
}
__device__ __forceinline__ float bf2f(unsigned short h) {
  return __uint_as_float(((unsigned int)h) << 16);
}
__device__ __forceinline__ unsigned int pkbf(float a, float b) {
  float2 f2; f2.x = a; f2.y = b;
  __hip_bfloat162 t = __float22bfloat162_rn(f2);
  unsigned int u;
  __builtin_memcpy(&u, &t, 4);
  return u;
}

// 256x64 @ 64x64 GEMM over 4 waves: A rows from A_lds (stride 72 u16), B cols from B_lds.
__device__ __forceinline__ void gemm64(const unsigned short* A_lds, const unsigned short* B_lds,
                                       int w, int l15, int quad, f32x4 acc[4][4]) {
#pragma unroll
  for (int tr = 0; tr < 4; ++tr)
#pragma unroll
    for (int tc = 0; tc < 4; ++tc)
      acc[tr][tc] = (f32x4){0.f, 0.f, 0.f, 0.f};
#pragma unroll
  for (int ms = 0; ms < 64; ms += 32) {
    bf16x8 af[4], bfr[4];
#pragma unroll
    for (int tr = 0; tr < 4; ++tr)
      af[tr] = *reinterpret_cast<const bf16x8*>(&A_lds[(64 * w + 16 * tr + l15) * 72 + ms + quad * 8]);
#pragma unroll
    for (int tc = 0; tc < 4; ++tc)
      bfr[tc] = *reinterpret_cast<const bf16x8*>(&B_lds[(16 * tc + l15) * 72 + ms + quad * 8]);
#pragma unroll
    for (int tr = 0; tr < 4; ++tr)
#pragma unroll
      for (int tc = 0; tc < 4; ++tc)
        acc[tr][tc] = __builtin_amdgcn_mfma_f32_16x16x32_bf16(af[tr], bfr[tc], acc[tr][tc], 0, 0, 0);
  }
}

// One block per (b, i-pair): 256 blocks x 512 threads (8 waves).
// Best-measured configuration of the session (R6, 125.4us): single launch, full weight
// prestage, 7 barriers (wave-local WAR elision), DS-lean P4, L2-warm prefetch of tail
// weights, single-wave dependent tail chain.
__global__ __launch_bounds__(512, 2) void k_all(
    const float* __restrict__ h, const float* __restrict__ x, const float* __restrict__ v,
    const float* __restrict__ ew1, const float* __restrict__ eb1,
    const float* __restrict__ ew2, const float* __restrict__ eb2,
    const float* __restrict__ semw, const float* __restrict__ semb,
    const float* __restrict__ pw1, const float* __restrict__ pb1,
    const float* __restrict__ pw2, const float* __restrict__ pb2,
    const float* __restrict__ nw1, const float* __restrict__ nb1,
    const float* __restrict__ nw2, const float* __restrict__ nb2,
    const float* __restrict__ vw1, const float* __restrict__ vb1,
    const float* __restrict__ vw2, const float* __restrict__ vmix,
    const float* __restrict__ lgam, float* __restrict__ out) {

  __shared__ __align__(16) unsigned short TH0[256 * 72];   // 36864 B: h_b -> T0 -> HE0 -> g0 tail scratch
  __shared__ __align__(16) unsigned short TH1[256 * 72];   // 36864 B: T1 -> HE1 -> g1 tail scratch
  __shared__ __align__(16) char R0[9216];   // W1a^T (GEMM1) -> sd0/cat0/cn0/hag0
  __shared__ __align__(16) char R1[9216];   // W2^T  (GEMM2) -> cat1/cn1/hag1
  __shared__ __align__(16) float SD1[2048]; // group-1 GEMM3 out (must NOT overlay R1: E2Tb still
                                            // read by group-0 GEMM2 when groups drift apart)
  __shared__ __align__(16) unsigned short E3T[16 * 72];    // [semw|vmix]^T rows 0..7, rows 8..15 zeroed
  __shared__ __align__(16) float4 unit_l[2][256];          // .xyz = unit, .w = dn   (per i)
  __shared__ float w1dk[64];                               // ew1 distance row (staged pre-s1)
  __shared__ float eb1l[64];                               // eb1 (staged pre-s1)
  __shared__ __align__(16) float bms[512];                 // Bm partials (P0) -> P3 scratch

  const int bid = blockIdx.x;
  const int b   = bid >> 7;          // batch
  const int ip  = bid & 127;         // i-pair
  const int tid = threadIdx.x;
  const int g   = tid >> 8;          // group / i-half
  const int jt  = tid & 255;         // j role within group
  const int i_g = 2 * ip + g;
  const int bi  = (b << 8) | i_g;
  const int bj  = (b << 8) | jt;

  const int w8   = tid >> 6;         // wave 0..7
  const int lid  = tid & 63;
  const int wg   = w8 & 3;           // wave within group
  const int l15  = lid & 15;
  const int quad = lid >> 4;

  // ===== P-1: L2 warm of tail weights (issued FIRST; consumed only by the asm
  // keep-alive after s8, ~20us later -> latency fully hidden under P0-P4) =====
  float warm = 0.f;
  {
    warm += pw1[(2 * tid) * 16] + pw1[(2 * tid + 1) * 16];            // 16384 fl = 1024 lines
    warm += nw1[(3 * tid) * 16] + nw1[(3 * tid + 1) * 16] + nw1[(3 * tid + 2) * 16]; // 1536 lines
    if (tid < 256) warm += pw2[tid * 16] + nw2[tid * 16] + vw1[tid * 16];            // 256 lines each
    if (tid < 64)  warm += eb2[tid] + pb1[tid] + pb2[tid] + nb1[tid] +
                           nb2[tid] + vb1[tid] + vw2[tid];
  }

  unsigned short* E2Ta = (unsigned short*)R0;
  unsigned short* E2Tb = (unsigned short*)R1;
  unsigned short* THg  = g ? TH1 : TH0;
  char* Rg = g ? R1 : R0;
  float*  sd_g  = g ? SD1 : (float*)R0;       // [256*8] fp32 GEMM3 out
  float4* cat_g = (float4*)Rg;                // [256] comb_att (writes post-B2; E2T* reads all pre-B1)
  float*  cn_g  = (float*)(Rg + 4096);        // [256] comb_norm
  float*  hag_g = (float*)(Rg + 5120);        // [256] h_agg
  // P3 scratch on bms (ep1 bms reads are pre-s3; these writes are post-s3):
  float4* scS   = (float4*)bms + g * 8;       // 8 slots / group
  float4* scP   = (float4*)bms + 16 + g * 4;  // 4 slots / group
  float4* scD   = (float4*)bms + 24 + g * 4;  // 4 slots / group
  float*  dvs_g = bms + 128 + g * 4;          // 3 floats / group

  // ================= P0: staging (ALL weights prefetched here) =================
  const float xi0 = x[bi * 3 + 0], xi1 = x[bi * 3 + 1], xi2 = x[bi * 3 + 2];
  const float dx = x[bj * 3 + 0] - xi0;
  const float dy = x[bj * 3 + 1] - xi1;
  const float dz = x[bj * 3 + 2] - xi2;
  const float dn = sqrtf(dx * dx + dy * dy + dz * dz + EPSV);
  const float invn = rcp_f(dn + EPSV);
  const float ux = dx * invn, uy = dy * invn, uz = dz * invn;
  unit_l[g][jt] = make_float4(ux, uy, uz, dn);

  {
    const float4* hb4 = reinterpret_cast<const float4*>(h + (size_t)(b << 8) * 64);
#pragma unroll
    for (int q = 0; q < 8; ++q) {
      int idx = q * 512 + tid;            // 0..4095 float4s
      float4 f4 = hb4[idx];
      int row = idx >> 4, c4 = idx & 15;
      uint2 pk;
      pk.x = pkbf(f4.x, f4.y);
      pk.y = pkbf(f4.z, f4.w);
      *reinterpret_cast<uint2*>(&TH0[row * 72 + c4 * 4]) = pk;
    }
  }
  // stage W1a^T and W2^T
#pragma unroll
  for (int q = 0; q < 8; ++q) {
    int idx = q * 512 + tid;              // f*64+k
    E2Ta[(idx & 63) * 72 + (idx >> 6)] = f2bf(ew1[idx]);
  }
#pragma unroll
  for (int q = 0; q < 8; ++q) {
    int idx = q * 512 + tid;
    E2Tb[(idx & 63) * 72 + (idx >> 6)] = f2bf(ew2[idx]);
  }
  // stage E3T = [semw | vmix]^T (rows 0..7); zero rows 8..15
  {
    int n = tid >> 6, kk = tid & 63;      // n 0..7
    E3T[n * 72 + kk] = f2bf((n < 4) ? semw[kk * 4 + n] : vmix[kk * 4 + (n - 4)]);
    E3T[(8 + n) * 72 + kk] = 0;
  }
  // w1dk / eb1 staged BEFORE s1 (read in ep1, which no longer has its own barrier)
  if (tid < 64) { w1dk[tid] = ew1[128 * 64 + tid]; eb1l[tid] = eb1[tid]; }
  // Bm partials for BOTH i's (fp32 exact); strip s == wave-in-group
  {
    int s = jt >> 6, k = jt & 63;
    const float* hrow = h + (size_t)bi * 64;     // wave-uniform -> scalar loads
    float bp = 0.f;
#pragma unroll
    for (int f2 = 0; f2 < 16; ++f2) {
      int f = s * 16 + f2;
      bp += hrow[f] * ew1[(64 + f) * 64 + k];
    }
    bms[g * 256 + s * 64 + k] = bp;
  }
  __syncthreads();                                               // s1

  // ================= P1: GEMM1 (h_b @ W1a), 8 waves x 32 rows — ONCE for both i's =================
  f32x4 acc1[2][4];
#pragma unroll
  for (int tr = 0; tr < 2; ++tr)
#pragma unroll
    for (int tc = 0; tc < 4; ++tc)
      acc1[tr][tc] = (f32x4){0.f, 0.f, 0.f, 0.f};
#pragma unroll
  for (int ms = 0; ms < 64; ms += 32) {
    bf16x8 af[2], bfr[4];
#pragma unroll
    for (int tr = 0; tr < 2; ++tr)
      af[tr] = *reinterpret_cast<const bf16x8*>(&TH0[(32 * w8 + 16 * tr + l15) * 72 + ms + quad * 8]);
#pragma unroll
    for (int tc = 0; tc < 4; ++tc)
      bfr[tc] = *reinterpret_cast<const bf16x8*>(&E2Ta[(16 * tc + l15) * 72 + ms + quad * 8]);
#pragma unroll
    for (int tr = 0; tr < 2; ++tr)
#pragma unroll
      for (int tc = 0; tc < 4; ++tc)
        acc1[tr][tc] = __builtin_amdgcn_mfma_f32_16x16x32_bf16(af[tr], bfr[tc], acc1[tr][tc], 0, 0, 0);
  }
  // NO barrier: epilogue rewrites exactly the rows [32w8,32w8+32) this wave read (wave-local WAR).

  // epilogue: T_i = silu(A + addk_i + dn_i*w1dk) -> TH0 / TH1 ; addk folded (bms synced by s1)
#pragma unroll
  for (int tc = 0; tc < 4; ++tc) {
    int kc = 16 * tc + l15;
    float wd = w1dk[kc];
    float eb = eb1l[kc];
    float ak0 = eb + bms[kc] + bms[64 + kc] + bms[128 + kc] + bms[192 + kc];
    float ak1 = eb + bms[256 + kc] + bms[320 + kc] + bms[384 + kc] + bms[448 + kc];
#pragma unroll
    for (int tr = 0; tr < 2; ++tr)
#pragma unroll
      for (int r = 0; r < 4; ++r) {
        int row = 32 * w8 + 16 * tr + quad * 4 + r;
        float a = acc1[tr][tc][r];
        float d0 = unit_l[0][row].w, d1 = unit_l[1][row].w;
        TH0[row * 72 + kc] = f2bf(silu_f(a + ak0 + d0 * wd));
        TH1[row * 72 + kc] = f2bf(silu_f(a + ak1 + d1 * wd));
      }
  }
  __syncthreads();                                               // s3 (T rows cross waves)

  // ================= P2: GEMM2 (HE_g = T_g @ W2), 4 waves per group =================
  f32x4 acc2[4][4];
  gemm64(THg, E2Tb, wg, l15, quad, acc2);
  // NO barrier: ep2 rewrites the wave's own A rows [64wg,64wg+64) (wave-local WAR).
#pragma unroll
  for (int tc = 0; tc < 4; ++tc) {
    float b2 = eb2[16 * tc + l15];
#pragma unroll
    for (int tr = 0; tr < 4; ++tr)
#pragma unroll
      for (int r = 0; r < 4; ++r) {
        int row = 64 * wg + 16 * tr + quad * 4 + r;
        THg[row * 72 + 16 * tc + l15] = f2bf(silu_f(acc2[tr][tc][r] + b2));
      }
  }
  // NO barrier: GEMM3 reads the wave's own rows (same-wave RAW, DS in-order).

  // ================= P2b: GEMM3 (HE_g @ [semw|vmix]) =================
  f32x4 acc3[4];
#pragma unroll
  for (int tr = 0; tr < 4; ++tr) acc3[tr] = (f32x4){0.f, 0.f, 0.f, 0.f};
#pragma unroll
  for (int ms = 0; ms < 64; ms += 32) {
    bf16x8 b3 = *reinterpret_cast<const bf16x8*>(&E3T[l15 * 72 + ms + quad * 8]);
#pragma unroll
    for (int tr = 0; tr < 4; ++tr) {
      bf16x8 a3 = *reinterpret_cast<const bf16x8*>(&THg[(64 * wg + 16 * tr + l15) * 72 + ms + quad * 8]);
      acc3[tr] = __builtin_amdgcn_mfma_f32_16x16x32_bf16(a3, b3, acc3[tr], 0, 0, 0);
    }
  }
  // sd_0 overlays R0 (E2Ta: all reads done pre-s3); sd_1 = dedicated SD1.
  if (l15 < 8) {
#pragma unroll
    for (int tr = 0; tr < 4; ++tr)
#pragma unroll
      for (int r = 0; r < 4; ++r)
        sd_g[(64 * wg + 16 * tr + quad * 4 + r) * 8 + l15] = acc3[tr][r];
  }
  // NO barrier: thread jt reads sd rows [64wg,64wg+64) written by its own wave.

  // ================= P3: attentions (thread = (g, j=jt)), 3 barriers =================
  float4 s01 = *reinterpret_cast<const float4*>(sd_g + jt * 8);       // sem logits (pre-bias)
  float4 s23 = *reinterpret_cast<const float4*>(sd_g + jt * 8 + 4);   // vmix dots
  float4 sbv = *reinterpret_cast<const float4*>(semb);
  const float diag = (jt == i_g) ? INFV : 0.0f;
  float4 sl;
  sl.x = s01.x + sbv.x; sl.y = s01.y + sbv.y; sl.z = s01.z + sbv.z; sl.w = s01.w + sbv.w;
  sl.x = ((sl.x > 0.f) ? sl.x : 0.2f * sl.x) - diag;
  sl.y = ((sl.y > 0.f) ? sl.y : 0.2f * sl.y) - diag;
  sl.z = ((sl.z > 0.f) ? sl.z : 0.2f * sl.z) - diag;
  sl.w = ((sl.w > 0.f) ? sl.w : 0.2f * sl.w) - diag;

  float4 lg4 = *reinterpret_cast<const float4*>(lgam);
  const float dni = dn + diag;
  float4 e_eu = make_float4(__expf(-dni * __expf(lg4.x)), __expf(-dni * __expf(lg4.y)),
                            __expf(-dni * __expf(lg4.z)), __expf(-dni * __expf(lg4.w)));
  // sem logits: LeakyReLU outputs << 88 off-diagonal; diag -1e5 -> exp == 0.
  float4 e_sem = make_float4(__expf(sl.x), __expf(sl.y), __expf(sl.z), __expf(sl.w));

  float4 a8 = e_eu, b8 = e_sem;
#pragma unroll
  for (int off = 32; off >= 1; off >>= 1) {
    a8.x += __shfl_xor(a8.x, off); a8.y += __shfl_xor(a8.y, off);
    a8.z += __shfl_xor(a8.z, off); a8.w += __shfl_xor(a8.w, off);
    b8.x += __shfl_xor(b8.x, off); b8.y += __shfl_xor(b8.y, off);
    b8.z += __shfl_xor(b8.z, off); b8.w += __shfl_xor(b8.w, off);
  }
  if (lid == 0) { scS[wg] = a8; scS[4 + wg] = b8; }
  __syncthreads();   // B1 (also: all sd/E2T reads precede cat_g writes)
  float4 Se, Ss;
  {
    float4 r0 = scS[0], r1 = scS[1], r2 = scS[2], r3 = scS[3];
    Se = make_float4(r0.x + r1.x + r2.x + r3.x, r0.y + r1.y + r2.y + r3.y,
                     r0.z + r1.z + r2.z + r3.z, r0.w + r1.w + r2.w + r3.w);
    float4 s0 = scS[4], s1 = scS[5], s2 = scS[6], s3 = scS[7];
    Ss = make_float4(s0.x + s1.x + s2.x + s3.x, s0.y + s1.y + s2.y + s3.y,
                     s0.z + s1.z + s2.z + s3.z, s0.w + s1.w + s2.w + s3.w);
  }

  float4 p = make_float4((e_eu.x * rcp_f(Se.x)) * (e_sem.x * rcp_f(Ss.x)),
                         (e_eu.y * rcp_f(Se.y)) * (e_sem.y * rcp_f(Ss.y)),
                         (e_eu.z * rcp_f(Se.z)) * (e_sem.z * rcp_f(Ss.z)),
                         (e_eu.w * rcp_f(Se.w)) * (e_sem.w * rcp_f(Ss.w)));
  float4 ep = make_float4(__expf(p.x), __expf(p.y), __expf(p.z), __expf(p.w));
  float4 sp8 = ep;
#pragma unroll
  for (int off = 32; off >= 1; off >>= 1) {
    sp8.x += __shfl_xor(sp8.x, off); sp8.y += __shfl_xor(sp8.y, off);
    sp8.z += __shfl_xor(sp8.z, off); sp8.w += __shfl_xor(sp8.w, off);
  }
  if (lid == 0) scP[wg] = sp8;
  __syncthreads();   // B2
  float4 Sp;
  {
    float4 r0 = scP[0], r1 = scP[1], r2 = scP[2], r3 = scP[3];
    Sp = make_float4(r0.x + r1.x + r2.x + r3.x, r0.y + r1.y + r2.y + r3.y,
                     r0.z + r1.z + r2.z + r3.z, r0.w + r1.w + r2.w + r3.w);
  }
  float4 catt = make_float4(ep.x * rcp_f(Sp.x), ep.y * rcp_f(Sp.y),
                            ep.z * rcp_f(Sp.z), ep.w * rcp_f(Sp.w));
  cat_g[jt] = catt;   // sd_g fully consumed before B1

  float s = catt.x * s23.x + catt.y * s23.y + catt.z * s23.z + catt.w * s23.w;
  float dvx = s * ux, dvy = s * uy, dvz = s * uz;
#pragma unroll
  for (int off = 32; off >= 1; off >>= 1) {
    dvx += __shfl_xor(dvx, off); dvy += __shfl_xor(dvy, off); dvz += __shfl_xor(dvz, off);
  }
  if (lid == 0) scD[wg] = make_float4(dvx, dvy, dvz, 0.f);
  __syncthreads();   // B3 (publishes cat_g for P4)
  if (jt == 0) {
    float4 r0 = scD[0], r1 = scD[1], r2 = scD[2], r3 = scD[3];
    const float inv = 1.0f / 256.0f;
    dvs_g[0] = (r0.x + r1.x + r2.x + r3.x) * inv;
    dvs_g[1] = (r0.y + r1.y + r2.y + r3.y) * inv;
    dvs_g[2] = (r0.z + r1.z + r2.z + r3.z) * inv;
  }

  // ========== P4: comb_sum / h_agg (DS-lean remap) ==========
  {
    const int jg   = lid >> 2;               // 0..15
    const int ksub = lid & 3;                // 0..3
    const int kb   = 16 * wg + 4 * ksub;     // 4 consecutive k's
    float agg[4][4], ax[4][4], ay[4][4], az[4][4];
#pragma unroll
    for (int kk = 0; kk < 4; ++kk)
#pragma unroll
      for (int hd = 0; hd < 4; ++hd) {
        agg[kk][hd] = 0.f; ax[kk][hd] = 0.f; ay[kk][hd] = 0.f; az[kk][hd] = 0.f;
      }
#pragma unroll 4
    for (int jr = 0; jr < 16; ++jr) {
      int jj = jr * 16 + jg;
      ushort4 hv4 = *reinterpret_cast<const ushort4*>(&THg[jj * 72 + kb]);
      float4 ca = cat_g[jj];
      float4 u  = unit_l[g][jj];
      float hev[4] = { bf2f(hv4.x), bf2f(hv4.y), bf2f(hv4.z), bf2f(hv4.w) };
#pragma unroll
      for (int kk = 0; kk < 4; ++kk) {
        float c0 = hev[kk] * ca.x, c1 = hev[kk] * ca.y, c2 = hev[kk] * ca.z, c3 = hev[kk] * ca.w;
        agg[kk][0] += c0; agg[kk][1] += c1; agg[kk][2] += c2; agg[kk][3] += c3;
        ax[kk][0] += c0 * u.x; ay[kk][0] += c0 * u.y; az[kk][0] += c0 * u.z;
        ax[kk][1] += c1 * u.x; ay[kk][1] += c1 * u.y; az[kk][1] += c1 * u.z;
        ax[kk][2] += c2 * u.x; ay[kk][2] += c2 * u.y; az[kk][2] += c2 * u.z;
        ax[kk][3] += c3 * u.x; ay[kk][3] += c3 * u.y; az[kk][3] += c3 * u.z;
      }
    }
#pragma unroll
    for (int off = 4; off <= 32; off <<= 1)
#pragma unroll
      for (int kk = 0; kk < 4; ++kk)
#pragma unroll
        for (int hd = 0; hd < 4; ++hd) {
          agg[kk][hd] += __shfl_xor(agg[kk][hd], off);
          ax[kk][hd]  += __shfl_xor(ax[kk][hd], off);
          ay[kk][hd]  += __shfl_xor(ay[kk][hd], off);
          az[kk][hd]  += __shfl_xor(az[kk][hd], off);
        }
    if (jg == 0) {
      const float inv = 1.0f / 256.0f;
#pragma unroll
      for (int kk = 0; kk < 4; ++kk) {
        int k = kb + kk;
        f32x4 cnv, hgv;
#pragma unroll
        for (int hd = 0; hd < 4; ++hd) {
          float cx = ax[kk][hd] * inv, cy = ay[kk][hd] * inv, cz = az[kk][hd] * inv;
          cnv[hd] = cx * cx + cy * cy + cz * cz;
          hgv[hd] = agg[kk][hd];
        }
        *reinterpret_cast<f32x4*>(&cn_g[k * 4])  = cnv;
        *reinterpret_cast<f32x4*>(&hag_g[k * 4]) = hgv;
      }
    }
  }
  __syncthreads();                                               // s8: hag cross-wave; THg freed

  // warm value consumed here: forces the prefetch loads to retire (long done by now)
  asm volatile("" :: "v"(warm));

  // ============== P5a: tail stage A, 4-wave parallel per group ==============
  {
    const int k = lid;
    float* tmpg = (float*)THg;                 // THg free after s8
    float a1 = 0.f;
#pragma unroll 16
    for (int m2 = 0; m2 < 64; ++m2) {
      int m = 64 * wg + m2;
      a1 += cn_g[m] * pw1[m * 64 + k];
    }
    tmpg[wg * 64 + k] = a1;
    if (wg == 1 || wg == 2) {
      float a2 = 0.f;
      int base = (wg - 1) * 128;
#pragma unroll 16
      for (int m2 = 0; m2 < 128; ++m2) {
        int m = base + m2;
        a2 += hag_g[m] * nw1[(64 + m) * 64 + k];
      }
      tmpg[256 + (wg - 1) * 64 + k] = a2;
    } else if (wg == 3) {
      float a2 = 0.f;
      const float* hrow = h + (size_t)bi * 64;
#pragma unroll 16
      for (int m = 0; m < 64; ++m) a2 += hrow[m] * nw1[m * 64 + k];
      tmpg[384 + k] = a2;
    }
  }
  __syncthreads();                                               // s9

  // ============== P5b: dependent chain, one wave per group, zero barriers ==============
  if (wg == 0) {
    const int k = lid;
    float* tmpg = (float*)THg;
    float* sh2  = tmpg + 512;                 // wave-local scratch (lgkmcnt-ordered)

    float m1 = silu_f(pb1[k] + tmpg[k] + tmpg[64 + k] + tmpg[128 + k] + tmpg[192 + k]);
    sh2[k] = m1;

    // post2: 64 -> 64
    float a = 0.f;
#pragma unroll 16
    for (int m = 0; m < 64; ++m) a += sh2[m] * pw2[m * 64 + k];
    float hcomb = silu_f(pb2[k] + a);
    sh2[64 + k] = hcomb;

    // node1: add hcomb part to precomputed h/hag partials
    a = nb1[k] + tmpg[256 + k] + tmpg[320 + k] + tmpg[384 + k];
#pragma unroll 16
    for (int m = 0; m < 64; ++m) a += sh2[64 + m] * nw1[(320 + m) * 64 + k];
    sh2[128 + k] = silu_f(a);

    // node2: 64 -> 64, residual
    a = 0.f;
#pragma unroll 16
    for (int m = 0; m < 64; ++m) a += sh2[128 + m] * nw2[m * 64 + k];
    float hn = h[(size_t)bi * 64 + k] + silu_f(nb2[k] + a);
    out[(size_t)bi * 64 + k] = hn;
    sh2[192 + k] = hn;

    // vel: 64 -> 64 -> scalar
    a = 0.f;
#pragma unroll 16
    for (int m = 0; m < 64; ++m) a += sh2[192 + m] * vw1[m * 64 + k];
    float vh = silu_f(vb1[k] + a) * vw2[k];
#pragma unroll
    for (int off = 32; off >= 1; off >>= 1) vh += __shfl_xor(vh, off);

    if (k == 0) {
      const float xi[3] = {xi0, xi1, xi2};
#pragma unroll
      for (int d = 0; d < 3; ++d) {
        float vn = dvs_g[d] + vh * v[bi * 3 + d];
        out[32768 + bi * 3 + d] = xi[d] + vn;
        out[34304 + bi * 3 + d] = vn;
      }
    }
  }
}

extern "C" void kernel_launch(void* const* d_in, const int* in_sizes, int n_in,
                              void* d_out, int out_size, void* d_ws, size_t ws_size,
                              hipStream_t stream) {
  const float* h    = (const float*)d_in[0];
  const float* x    = (const float*)d_in[1];
  const float* v    = (const float*)d_in[2];
  const float* ew1  = (const float*)d_in[3];
  const float* eb1  = (const float*)d_in[4];
  const float* ew2  = (const float*)d_in[5];
  const float* eb2  = (const float*)d_in[6];
  const float* semw = (const float*)d_in[7];
  const float* semb = (const float*)d_in[8];
  const float* pw1  = (const float*)d_in[9];
  const float* pb1  = (const float*)d_in[10];
  const float* pw2  = (const float*)d_in[11];
  const float* pb2  = (const float*)d_in[12];
  const float* nw1  = (const float*)d_in[13];
  const float* nb1  = (const float*)d_in[14];
  const float* nw2  = (const float*)d_in[15];
  const float* nb2  = (const float*)d_in[16];
  const float* vw1  = (const float*)d_in[17];
  const float* vb1  = (const float*)d_in[18];
  const float* vw2  = (const float*)d_in[19];
  const float* vmix = (const float*)d_in[20];
  const float* lgam = (const float*)d_in[21];
  float* out = (float*)d_out;

  k_all<<<256, 512, 0, stream>>>(h, x, v, ew1, eb1, ew2, eb2, semw, semb,
                                 pw1, pb1, pw2, pb2, nw1, nb1, nw2, nb2,
                                 vw1, vb1, vw2, vmix, lgam, out);
}